// Round 5
// baseline (27054.929 us; speedup 1.0000x reference)
//
#include <hip/hip_runtime.h>
#include <cstdint>
#include <climits>

#define N 8192
#define D 64
#define H 128
#define O 64
#define KNB 16
#define NE (N*KNB)        // 131072
#define ETOT (NE + N)     // 139264
#define OUT0 (N*D)        // 524288

__device__ __forceinline__ float bf2f(unsigned short u){
    union { unsigned int u; float f; } v; v.u = ((unsigned int)u) << 16; return v.f;
}
__device__ __forceinline__ unsigned short f2bf(float f){
    union { float f; unsigned int u; } v; v.f = f;
    unsigned int r = v.u + 0x7FFFu + ((v.u >> 16) & 1u);   // RNE
    return (unsigned short)(r >> 16);
}

// ---------------- dtype probe: 1=bf16 inputs, 0=fp32 inputs ----------------
__global__ void k_probe(const unsigned short* __restrict__ x, int* __restrict__ flag){
    __shared__ int cnt;
    if (threadIdx.x == 0) cnt = 0;
    __syncthreads();
    unsigned short u = x[2*threadIdx.x];
    int e = (u >> 7) & 0xFF;
    int ok = (u == 0) || (e >= 0x60 && e <= 0x85);
    unsigned long long m = __ballot(ok);
    if ((threadIdx.x & 63) == 0) atomicAdd(&cnt, __popcll(m));
    __syncthreads();
    if (threadIdx.x == 0) *flag = (cnt >= 128) ? 1 : 0;
}

// ---------------- generic input convert -> fp32 ----------------
__global__ void k_cvt(const void* __restrict__ src, float* __restrict__ dst,
                      int n, const int* __restrict__ flag){
    int i = blockIdx.x*256 + threadIdx.x;
    if (i >= n) return;
    if (*flag) dst[i] = bf2f(((const unsigned short*)src)[i]);
    else       dst[i] = ((const float*)src)[i];
}

// ---------------- row norms: EXACT numpy fp32 pairwise semantics ----------------
__global__ void k_prep(const float* __restrict__ xf, float* __restrict__ nrmf){
    int i = blockIdx.x*64 + threadIdx.x;
    const float* xr = xf + i*D;
    float r[8];
    #pragma unroll
    for (int q = 0; q < 8; ++q) r[q] = __fmul_rn(xr[q], xr[q]);
    #pragma unroll
    for (int b = 8; b < 64; b += 8)
        #pragma unroll
        for (int q = 0; q < 8; ++q)
            r[q] = __fadd_rn(r[q], __fmul_rn(xr[b+q], xr[b+q]));
    float s = __fadd_rn(__fadd_rn(__fadd_rn(r[0],r[1]), __fadd_rn(r[2],r[3])),
                        __fadd_rn(__fadd_rn(r[4],r[5]), __fadd_rn(r[6],r[7])));
    nrmf[i] = __fsqrt_rn(s);
}

// ---------------- topk: 8 queries/block (1024 blocks), 2-way j-interleave ----
// Thread (q = tid>>5, m = tid&31): query i = blk*8+q, scans j0 = m+64s,
// j1 = j0+32, s = 0..127 (j ascending per thread -> tie semantics preserved).
// Pool layout [r*256+tid] = conflict-free merge reads (R3-proven).
__global__ __launch_bounds__(256, 4) void k_topk(const float* __restrict__ xf,
                                                 const float* __restrict__ nrmf,
                                                 int* __restrict__ topIdx,
                                                 float* __restrict__ ewArr){
    __shared__ float mv[4096];   // pool: [r*256 + tid]
    __shared__ int   mi[4096];
    __shared__ float cv[256];    // per-round candidates [q*32 + m]
    __shared__ int   ci[256];
    __shared__ int   cp[256];

    int tid = threadIdx.x;
    int q = tid >> 5, m = tid & 31;
    int i = blockIdx.x*8 + q;

    const float4* xip = (const float4*)(xf + (size_t)i*D);
    float4 xi4[16];
    #pragma unroll
    for (int c = 0; c < 16; ++c) xi4[c] = xip[c];
    float ni = nrmf[i];

    float lv[16]; int li[16];
    #pragma unroll
    for (int r = 0; r < 16; ++r){ lv[r] = -3.0e38f; li[r] = INT_MAX; }

    for (int s = 0; s < 128; ++s){
        int j0 = m + 64*s;
        int j1 = j0 + 32;
        const float4* A0 = (const float4*)(xf + (size_t)j0*D);
        const float4* A1 = (const float4*)(xf + (size_t)j1*D);
        float a0 = 0.0f, a1 = 0.0f;
        #pragma unroll
        for (int c = 0; c < 16; ++c){
            float4 b0 = A0[c], b1 = A1[c], xa = xi4[c];
            a0 = __fmaf_rn(b0.x, xa.x, a0);
            a0 = __fmaf_rn(b0.y, xa.y, a0);
            a0 = __fmaf_rn(b0.z, xa.z, a0);
            a0 = __fmaf_rn(b0.w, xa.w, a0);
            a1 = __fmaf_rn(b1.x, xa.x, a1);
            a1 = __fmaf_rn(b1.y, xa.y, a1);
            a1 = __fmaf_rn(b1.z, xa.z, a1);
            a1 = __fmaf_rn(b1.w, xa.w, a1);
        }
        float s0 = __fdiv_rn(a0, __fadd_rn(__fmul_rn(ni, nrmf[j0]), 1e-8f));
        float s1 = __fdiv_rn(a1, __fadd_rn(__fmul_rn(ni, nrmf[j1]), 1e-8f));
        if (j0 == i) s0 = -3.0e38f;
        if (j1 == i) s1 = -3.0e38f;
        if (s0 > lv[15]){
            lv[15] = s0; li[15] = j0;
            #pragma unroll
            for (int r = 15; r > 0; --r){
                if (lv[r] > lv[r-1]){
                    float tv = lv[r]; lv[r] = lv[r-1]; lv[r-1] = tv;
                    int ti = li[r]; li[r] = li[r-1]; li[r-1] = ti;
                }
            }
        }
        if (s1 > lv[15]){
            lv[15] = s1; li[15] = j1;
            #pragma unroll
            for (int r = 15; r > 0; --r){
                if (lv[r] > lv[r-1]){
                    float tv = lv[r]; lv[r] = lv[r-1]; lv[r-1] = tv;
                    int ti = li[r]; li[r] = li[r-1]; li[r-1] = ti;
                }
            }
        }
    }

    #pragma unroll
    for (int r = 0; r < 16; ++r){
        mv[r*256 + tid] = lv[r];
        mi[r*256 + tid] = li[r];
    }
    __syncthreads();

    for (int sel = 0; sel < 16; ++sel){
        float bv = -3.0e38f; int bi = INT_MAX; int bp = 0;
        #pragma unroll
        for (int r = 0; r < 16; ++r){
            int p = r*256 + tid;
            float v = mv[p]; int id = mi[p];
            if (v > bv || (v == bv && id < bi)){ bv = v; bi = id; bp = p; }
        }
        cv[q*32 + m] = bv; ci[q*32 + m] = bi; cp[q*32 + m] = bp;
        __syncthreads();
        if (tid < 8){
            int q2 = tid;
            float fv = -3.0e38f; int fi = INT_MAX; int fp = 0;
            #pragma unroll
            for (int c = 0; c < 32; ++c){
                float v = cv[q2*32 + c]; int id = ci[q2*32 + c];
                if (v > fv || (v == fv && id < fi)){ fv = v; fi = id; fp = cp[q2*32 + c]; }
            }
            int i2 = blockIdx.x*8 + q2;
            topIdx[i2*KNB + sel] = fi;
            ewArr [i2*KNB + sel] = (fv > 0.5f) ? fv : 0.0f;
            mv[fp] = -3.0e38f;
        }
        __syncthreads();
    }
}

// ---------------- degree / dinv ----------------
__global__ void k_deg_init(double* __restrict__ degD){
    int j = blockIdx.x*blockDim.x + threadIdx.x;
    if (j < N) degD[j] = 2.0;
}
__global__ void k_deg_scatter(const int* __restrict__ topIdx, const float* __restrict__ ewArr,
                              double* __restrict__ degD){
    int e = blockIdx.x*blockDim.x + threadIdx.x;
    if (e < NE){
        float w = ewArr[e];
        if (w > 0.0f) atomicAdd(&degD[topIdx[e]], (double)w);
    }
}
__global__ void k_dinv(const double* __restrict__ degD, float* __restrict__ dinv){
    int j = blockIdx.x*blockDim.x + threadIdx.x;
    if (j < N) dinv[j] = (float)(1.0 / sqrt(degD[j]));
}

// ---------------- dense matmuls ----------------
__global__ void k_gemm1(const float* __restrict__ xf, const float* __restrict__ W1,
                        float* __restrict__ h1){
    int id = blockIdx.x*256 + threadIdx.x;
    int i = id >> 7; int f = id & (H-1);
    const float* xr = xf + i*D;
    float acc = 0.f;
    #pragma unroll
    for (int k = 0; k < D; ++k) acc += xr[k] * W1[k*H + f];
    h1[id] = acc;
}
__global__ void k_gemm2(const float* __restrict__ z1, const float* __restrict__ W2,
                        float* __restrict__ h2){
    int id = blockIdx.x*256 + threadIdx.x;
    int i = id >> 6; int f = id & (O-1);
    const float* zr = z1 + i*H;
    float acc = 0.f;
    #pragma unroll
    for (int k = 0; k < H; ++k) acc += zr[k] * W2[k*O + f];
    h2[id] = acc;
}
__global__ void k_proj(const float* __restrict__ z2, const float* __restrict__ Wp,
                       const float* __restrict__ bp, float* __restrict__ z3){
    int id = blockIdx.x*256 + threadIdx.x;
    int i = id >> 6; int f = id & (D-1);
    const float* zr = z2 + i*O;
    float acc = bp[f];
    #pragma unroll
    for (int k = 0; k < O; ++k) acc += zr[k] * Wp[k*D + f];
    z3[id] = acc;
}

// ---------------- GCN aggregation ----------------
template<int F>
__global__ void k_agg_init(const float* __restrict__ h, const float* __restrict__ dinv,
                           float* __restrict__ agg){
    int id = blockIdx.x*256 + threadIdx.x;
    int j = id / F;
    float dj = dinv[j];
    agg[id] = 2.f * dj * dj * h[id];
}
template<int F>
__global__ void k_agg_scat(const int* __restrict__ topIdx, const float* __restrict__ ewArr,
                           const float* __restrict__ dinv, const float* __restrict__ h,
                           float* __restrict__ agg){
    int e = blockIdx.x; int f = threadIdx.x;
    float w = ewArr[e];
    if (w == 0.f) return;
    int s = e >> 4;
    int dn = topIdx[e];
    float c = dinv[s] * w * dinv[dn];
    atomicAdd(&agg[dn*F + f], c * h[s*F + f]);
}

// ---------------- bias + relu + layernorm ----------------
__global__ void k_post128(const float* __restrict__ agg, const float* __restrict__ b,
                          const float* __restrict__ g, const float* __restrict__ be,
                          float* __restrict__ z){
    __shared__ double s2[2];
    __shared__ double s3[2];
    int i = blockIdx.x; int f = threadIdx.x;
    float v = agg[i*H + f] + b[f];
    v = v > 0.f ? v : 0.f;
    int wid = f >> 6;
    double d = (double)v;
    for (int off = 32; off > 0; off >>= 1) d += __shfl_xor(d, off);
    if ((f & 63) == 0) s2[wid] = d;
    __syncthreads();
    double mu = (s2[0] + s2[1]) * (1.0/128.0);
    double dv = (double)v - mu;
    double qq = dv * dv;
    for (int off = 32; off > 0; off >>= 1) qq += __shfl_xor(qq, off);
    if ((f & 63) == 0) s3[wid] = qq;
    __syncthreads();
    double var = (s3[0] + s3[1]) * (1.0/128.0);
    double rs = 1.0 / sqrt(var + 1e-5);
    z[i*H + f] = (float)(dv * rs * (double)g[f] + (double)be[f]);
}
__global__ void k_post64(const float* __restrict__ agg, const float* __restrict__ b,
                         const float* __restrict__ g, const float* __restrict__ be,
                         float* __restrict__ z){
    int i = blockIdx.x; int f = threadIdx.x;
    float v = agg[i*O + f] + b[f];
    v = v > 0.f ? v : 0.f;
    double d = (double)v;
    for (int off = 32; off > 0; off >>= 1) d += __shfl_xor(d, off);
    double mu = d * (1.0/64.0);
    double dv = (double)v - mu;
    double qq = dv * dv;
    for (int off = 32; off > 0; off >>= 1) qq += __shfl_xor(qq, off);
    double var = qq * (1.0/64.0);
    double rs = 1.0 / sqrt(var + 1e-5);
    z[i*O + f] = (float)(dv * rs * (double)g[f] + (double)be[f]);
}

// ---------------- output stores (flag-branched dtype) ----------------
__global__ void k_store(const float* __restrict__ z3, void* __restrict__ outp,
                        const int* __restrict__ flag){
    int i = blockIdx.x*256 + threadIdx.x;
    float v = z3[i];
    if (*flag) ((unsigned short*)outp)[i] = f2bf(v);
    else       ((float*)outp)[i] = v;
}
__global__ void k_edges(const int* __restrict__ topIdx, const float* __restrict__ ewArr,
                        void* __restrict__ outp, const int* __restrict__ flag){
    int e = blockIdx.x*256 + threadIdx.x;
    if (e >= ETOT) return;
    int s, dn; float w;
    if (e < NE){ s = e >> 4; dn = topIdx[e]; w = ewArr[e]; }
    else       { s = e - NE; dn = s;        w = 1.0f; }
    if (*flag){
        unsigned short* o = (unsigned short*)outp;
        o[OUT0 + e]          = f2bf((float)s);
        o[OUT0 + ETOT + e]   = f2bf((float)dn);
        o[OUT0 + 2*ETOT + e] = f2bf(w);
    } else {
        float* o = (float*)outp;
        o[OUT0 + e]          = (float)s;
        o[OUT0 + ETOT + e]   = (float)dn;
        o[OUT0 + 2*ETOT + e] = w;
    }
}

extern "C" void kernel_launch(void* const* d_in, const int* in_sizes, int n_in,
                              void* d_out, int out_size, void* d_ws, size_t ws_size,
                              hipStream_t stream){
    char* ws = (char*)d_ws;
    int*    flag   = (int*)   (ws + 0);
    float*  w1f    = (float*) (ws + 4096);
    float*  b1f    = (float*) (ws + 36864);
    float*  g1f    = (float*) (ws + 37376);
    float*  be1f   = (float*) (ws + 37888);
    float*  w2f    = (float*) (ws + 38400);
    float*  b2f    = (float*) (ws + 71168);
    float*  g2f    = (float*) (ws + 71424);
    float*  be2f   = (float*) (ws + 71680);
    float*  wpf    = (float*) (ws + 71936);
    float*  bpf    = (float*) (ws + 88320);
    float*  xf     = (float*) (ws + 98304);      // 2 MB          -> 2195456
    float*  nrmf   = (float*) (ws + 2195456);    // 32 KB         -> 2228224
    int*    topIdx = (int*)   (ws + 2260992);    // 512 KB        -> 2785280
    float*  ewArr  = (float*) (ws + 2785280);    // 512 KB        -> 3309568
    double* degD   = (double*)(ws + 3309568);    // 64 KB         -> 3375104
    float*  dinv   = (float*) (ws + 3375104);    // 32 KB         -> 3407872
    float*  h1     = (float*) (ws + 3407872);    // 4 MB          -> 7602176
    float*  agg1   = (float*) (ws + 7602176);    // 4 MB          -> 11796480
    float*  z1     = (float*) (ws + 11796480);   // 4 MB          -> 15990784
    float*  h2     = h1;
    float*  agg2   = agg1;
    float*  z2     = z1;
    float*  z3     = h1;

    k_probe<<<1, 256, 0, stream>>>((const unsigned short*)d_in[0], flag);
    k_cvt<<<(N*D+255)/256, 256, 0, stream>>>(d_in[0], xf,  N*D, flag);
    k_cvt<<<(D*H+255)/256, 256, 0, stream>>>(d_in[1], w1f, D*H, flag);
    k_cvt<<<1, 256, 0, stream>>>(d_in[2], b1f,  H, flag);
    k_cvt<<<1, 256, 0, stream>>>(d_in[3], g1f,  H, flag);
    k_cvt<<<1, 256, 0, stream>>>(d_in[4], be1f, H, flag);
    k_cvt<<<(H*O+255)/256, 256, 0, stream>>>(d_in[5], w2f, H*O, flag);
    k_cvt<<<1, 256, 0, stream>>>(d_in[6], b2f,  O, flag);
    k_cvt<<<1, 256, 0, stream>>>(d_in[7], g2f,  O, flag);
    k_cvt<<<1, 256, 0, stream>>>(d_in[8], be2f, O, flag);
    k_cvt<<<(O*D+255)/256, 256, 0, stream>>>(d_in[9], wpf, O*D, flag);
    k_cvt<<<1, 256, 0, stream>>>(d_in[10], bpf, D, flag);

    k_prep<<<N/64, 64, 0, stream>>>(xf, nrmf);
    k_topk<<<N/8, 256, 0, stream>>>(xf, nrmf, topIdx, ewArr);
    k_deg_init<<<N/256, 256, 0, stream>>>(degD);
    k_deg_scatter<<<NE/256, 256, 0, stream>>>(topIdx, ewArr, degD);
    k_dinv<<<N/256, 256, 0, stream>>>(degD, dinv);

    k_gemm1<<<(N*H)/256, 256, 0, stream>>>(xf, w1f, h1);
    k_agg_init<H><<<(N*H)/256, 256, 0, stream>>>(h1, dinv, agg1);
    k_agg_scat<H><<<NE, H, 0, stream>>>(topIdx, ewArr, dinv, h1, agg1);
    k_post128<<<N, H, 0, stream>>>(agg1, b1f, g1f, be1f, z1);

    k_gemm2<<<(N*O)/256, 256, 0, stream>>>(z1, w2f, h2);
    k_agg_init<O><<<(N*O)/256, 256, 0, stream>>>(h2, dinv, agg2);
    k_agg_scat<O><<<NE, O, 0, stream>>>(topIdx, ewArr, dinv, h2, agg2);
    k_post64<<<N, O, 0, stream>>>(agg2, b2f, g2f, be2f, z2);

    k_proj<<<(N*D)/256, 256, 0, stream>>>(z2, wpf, bpf, z3);
    k_store<<<(N*D)/256, 256, 0, stream>>>(z3, d_out, flag);
    k_edges<<<(ETOT+255)/256, 256, 0, stream>>>(topIdx, ewArr, d_out, flag);
}

// Round 6
// 2085.512 us; speedup vs baseline: 12.9728x; 12.9728x over previous
//
#include <hip/hip_runtime.h>
#include <cstdint>
#include <climits>

#define N 8192
#define D 64
#define H 128
#define O 64
#define KNB 16
#define NE (N*KNB)        // 131072
#define ETOT (NE + N)     // 139264
#define OUT0 (N*D)        // 524288

__device__ __forceinline__ float bf2f(unsigned short u){
    union { unsigned int u; float f; } v; v.u = ((unsigned int)u) << 16; return v.f;
}
__device__ __forceinline__ unsigned short f2bf(float f){
    union { float f; unsigned int u; } v; v.f = f;
    unsigned int r = v.u + 0x7FFFu + ((v.u >> 16) & 1u);   // RNE
    return (unsigned short)(r >> 16);
}

// ---------------- dtype probe: 1=bf16 inputs, 0=fp32 inputs ----------------
__global__ void k_probe(const unsigned short* __restrict__ x, int* __restrict__ flag){
    __shared__ int cnt;
    if (threadIdx.x == 0) cnt = 0;
    __syncthreads();
    unsigned short u = x[2*threadIdx.x];
    int e = (u >> 7) & 0xFF;
    int ok = (u == 0) || (e >= 0x60 && e <= 0x85);
    unsigned long long m = __ballot(ok);
    if ((threadIdx.x & 63) == 0) atomicAdd(&cnt, __popcll(m));
    __syncthreads();
    if (threadIdx.x == 0) *flag = (cnt >= 128) ? 1 : 0;
}

// ---------------- generic input convert -> fp32 ----------------
__global__ void k_cvt(const void* __restrict__ src, float* __restrict__ dst,
                      int n, const int* __restrict__ flag){
    int i = blockIdx.x*256 + threadIdx.x;
    if (i >= n) return;
    if (*flag) dst[i] = bf2f(((const unsigned short*)src)[i]);
    else       dst[i] = ((const float*)src)[i];
}

// ---------------- row norms: EXACT numpy fp32 pairwise semantics ----------------
__global__ void k_prep(const float* __restrict__ xf, float* __restrict__ nrmf){
    int i = blockIdx.x*64 + threadIdx.x;
    const float* xr = xf + i*D;
    float r[8];
    #pragma unroll
    for (int q = 0; q < 8; ++q) r[q] = __fmul_rn(xr[q], xr[q]);
    #pragma unroll
    for (int b = 8; b < 64; b += 8)
        #pragma unroll
        for (int q = 0; q < 8; ++q)
            r[q] = __fadd_rn(r[q], __fmul_rn(xr[b+q], xr[b+q]));
    float s = __fadd_rn(__fadd_rn(__fadd_rn(r[0],r[1]), __fadd_rn(r[2],r[3])),
                        __fadd_rn(__fadd_rn(r[4],r[5]), __fadd_rn(r[6],r[7])));
    nrmf[i] = __fsqrt_rn(s);
}

// ---------------- topk: 8 queries/block (1024 blocks), 2-way j-interleave ----
// Thread (q = tid>>5, m = tid&31): query i = blk*8+q, scans j0 = m+64s,
// j1 = j0+32, s = 0..127 (j ascending per thread -> tie semantics preserved).
// Pool layout [r*256+tid] = conflict-free merge reads.
// NOTE: plain __launch_bounds__(256) — adding a min-waves/EU arg capped VGPR
// at 64 and spilled xi4/lv/li to scratch (R5: 49 GB writes, 27 ms). VGPR=120
// still admits 4 waves/EU, so occupancy is unchanged without the cap.
__global__ __launch_bounds__(256) void k_topk(const float* __restrict__ xf,
                                              const float* __restrict__ nrmf,
                                              int* __restrict__ topIdx,
                                              float* __restrict__ ewArr){
    __shared__ float mv[4096];   // pool: [r*256 + tid]
    __shared__ int   mi[4096];
    __shared__ float cv[256];    // per-round candidates [q*32 + m]
    __shared__ int   ci[256];
    __shared__ int   cp[256];

    int tid = threadIdx.x;
    int q = tid >> 5, m = tid & 31;
    int i = blockIdx.x*8 + q;

    const float4* xip = (const float4*)(xf + (size_t)i*D);
    float4 xi4[16];
    #pragma unroll
    for (int c = 0; c < 16; ++c) xi4[c] = xip[c];
    float ni = nrmf[i];

    float lv[16]; int li[16];
    #pragma unroll
    for (int r = 0; r < 16; ++r){ lv[r] = -3.0e38f; li[r] = INT_MAX; }

    for (int s = 0; s < 128; ++s){
        int j0 = m + 64*s;
        int j1 = j0 + 32;
        const float4* A0 = (const float4*)(xf + (size_t)j0*D);
        const float4* A1 = (const float4*)(xf + (size_t)j1*D);
        float a0 = 0.0f, a1 = 0.0f;
        #pragma unroll
        for (int c = 0; c < 16; ++c){
            float4 b0 = A0[c], b1 = A1[c], xa = xi4[c];
            a0 = __fmaf_rn(b0.x, xa.x, a0);
            a0 = __fmaf_rn(b0.y, xa.y, a0);
            a0 = __fmaf_rn(b0.z, xa.z, a0);
            a0 = __fmaf_rn(b0.w, xa.w, a0);
            a1 = __fmaf_rn(b1.x, xa.x, a1);
            a1 = __fmaf_rn(b1.y, xa.y, a1);
            a1 = __fmaf_rn(b1.z, xa.z, a1);
            a1 = __fmaf_rn(b1.w, xa.w, a1);
        }
        float s0 = __fdiv_rn(a0, __fadd_rn(__fmul_rn(ni, nrmf[j0]), 1e-8f));
        float s1 = __fdiv_rn(a1, __fadd_rn(__fmul_rn(ni, nrmf[j1]), 1e-8f));
        if (j0 == i) s0 = -3.0e38f;
        if (j1 == i) s1 = -3.0e38f;
        if (s0 > lv[15]){
            lv[15] = s0; li[15] = j0;
            #pragma unroll
            for (int r = 15; r > 0; --r){
                if (lv[r] > lv[r-1]){
                    float tv = lv[r]; lv[r] = lv[r-1]; lv[r-1] = tv;
                    int ti = li[r]; li[r] = li[r-1]; li[r-1] = ti;
                }
            }
        }
        if (s1 > lv[15]){
            lv[15] = s1; li[15] = j1;
            #pragma unroll
            for (int r = 15; r > 0; --r){
                if (lv[r] > lv[r-1]){
                    float tv = lv[r]; lv[r] = lv[r-1]; lv[r-1] = tv;
                    int ti = li[r]; li[r] = li[r-1]; li[r-1] = ti;
                }
            }
        }
    }

    #pragma unroll
    for (int r = 0; r < 16; ++r){
        mv[r*256 + tid] = lv[r];
        mi[r*256 + tid] = li[r];
    }
    __syncthreads();

    for (int sel = 0; sel < 16; ++sel){
        float bv = -3.0e38f; int bi = INT_MAX; int bp = 0;
        #pragma unroll
        for (int r = 0; r < 16; ++r){
            int p = r*256 + tid;
            float v = mv[p]; int id = mi[p];
            if (v > bv || (v == bv && id < bi)){ bv = v; bi = id; bp = p; }
        }
        cv[q*32 + m] = bv; ci[q*32 + m] = bi; cp[q*32 + m] = bp;
        __syncthreads();
        if (tid < 8){
            int q2 = tid;
            float fv = -3.0e38f; int fi = INT_MAX; int fp = 0;
            #pragma unroll
            for (int c = 0; c < 32; ++c){
                float v = cv[q2*32 + c]; int id = ci[q2*32 + c];
                if (v > fv || (v == fv && id < fi)){ fv = v; fi = id; fp = cp[q2*32 + c]; }
            }
            int i2 = blockIdx.x*8 + q2;
            topIdx[i2*KNB + sel] = fi;
            ewArr [i2*KNB + sel] = (fv > 0.5f) ? fv : 0.0f;
            mv[fp] = -3.0e38f;
        }
        __syncthreads();
    }
}

// ---------------- degree / dinv ----------------
__global__ void k_deg_init(double* __restrict__ degD){
    int j = blockIdx.x*blockDim.x + threadIdx.x;
    if (j < N) degD[j] = 2.0;
}
__global__ void k_deg_scatter(const int* __restrict__ topIdx, const float* __restrict__ ewArr,
                              double* __restrict__ degD){
    int e = blockIdx.x*blockDim.x + threadIdx.x;
    if (e < NE){
        float w = ewArr[e];
        if (w > 0.0f) atomicAdd(&degD[topIdx[e]], (double)w);
    }
}
__global__ void k_dinv(const double* __restrict__ degD, float* __restrict__ dinv){
    int j = blockIdx.x*blockDim.x + threadIdx.x;
    if (j < N) dinv[j] = (float)(1.0 / sqrt(degD[j]));
}

// ---------------- dense matmuls ----------------
__global__ void k_gemm1(const float* __restrict__ xf, const float* __restrict__ W1,
                        float* __restrict__ h1){
    int id = blockIdx.x*256 + threadIdx.x;
    int i = id >> 7; int f = id & (H-1);
    const float* xr = xf + i*D;
    float acc = 0.f;
    #pragma unroll
    for (int k = 0; k < D; ++k) acc += xr[k] * W1[k*H + f];
    h1[id] = acc;
}
__global__ void k_gemm2(const float* __restrict__ z1, const float* __restrict__ W2,
                        float* __restrict__ h2){
    int id = blockIdx.x*256 + threadIdx.x;
    int i = id >> 6; int f = id & (O-1);
    const float* zr = z1 + i*H;
    float acc = 0.f;
    #pragma unroll
    for (int k = 0; k < H; ++k) acc += zr[k] * W2[k*O + f];
    h2[id] = acc;
}
__global__ void k_proj(const float* __restrict__ z2, const float* __restrict__ Wp,
                       const float* __restrict__ bp, float* __restrict__ z3){
    int id = blockIdx.x*256 + threadIdx.x;
    int i = id >> 6; int f = id & (D-1);
    const float* zr = z2 + i*O;
    float acc = bp[f];
    #pragma unroll
    for (int k = 0; k < O; ++k) acc += zr[k] * Wp[k*D + f];
    z3[id] = acc;
}

// ---------------- GCN aggregation ----------------
template<int F>
__global__ void k_agg_init(const float* __restrict__ h, const float* __restrict__ dinv,
                           float* __restrict__ agg){
    int id = blockIdx.x*256 + threadIdx.x;
    int j = id / F;
    float dj = dinv[j];
    agg[id] = 2.f * dj * dj * h[id];
}
template<int F>
__global__ void k_agg_scat(const int* __restrict__ topIdx, const float* __restrict__ ewArr,
                           const float* __restrict__ dinv, const float* __restrict__ h,
                           float* __restrict__ agg){
    int e = blockIdx.x; int f = threadIdx.x;
    float w = ewArr[e];
    if (w == 0.f) return;
    int s = e >> 4;
    int dn = topIdx[e];
    float c = dinv[s] * w * dinv[dn];
    atomicAdd(&agg[dn*F + f], c * h[s*F + f]);
}

// ---------------- bias + relu + layernorm ----------------
__global__ void k_post128(const float* __restrict__ agg, const float* __restrict__ b,
                          const float* __restrict__ g, const float* __restrict__ be,
                          float* __restrict__ z){
    __shared__ double s2[2];
    __shared__ double s3[2];
    int i = blockIdx.x; int f = threadIdx.x;
    float v = agg[i*H + f] + b[f];
    v = v > 0.f ? v : 0.f;
    int wid = f >> 6;
    double d = (double)v;
    for (int off = 32; off > 0; off >>= 1) d += __shfl_xor(d, off);
    if ((f & 63) == 0) s2[wid] = d;
    __syncthreads();
    double mu = (s2[0] + s2[1]) * (1.0/128.0);
    double dv = (double)v - mu;
    double qq = dv * dv;
    for (int off = 32; off > 0; off >>= 1) qq += __shfl_xor(qq, off);
    if ((f & 63) == 0) s3[wid] = qq;
    __syncthreads();
    double var = (s3[0] + s3[1]) * (1.0/128.0);
    double rs = 1.0 / sqrt(var + 1e-5);
    z[i*H + f] = (float)(dv * rs * (double)g[f] + (double)be[f]);
}
__global__ void k_post64(const float* __restrict__ agg, const float* __restrict__ b,
                         const float* __restrict__ g, const float* __restrict__ be,
                         float* __restrict__ z){
    int i = blockIdx.x; int f = threadIdx.x;
    float v = agg[i*O + f] + b[f];
    v = v > 0.f ? v : 0.f;
    double d = (double)v;
    for (int off = 32; off > 0; off >>= 1) d += __shfl_xor(d, off);
    double mu = d * (1.0/64.0);
    double dv = (double)v - mu;
    double qq = dv * dv;
    for (int off = 32; off > 0; off >>= 1) qq += __shfl_xor(qq, off);
    double var = qq * (1.0/64.0);
    double rs = 1.0 / sqrt(var + 1e-5);
    z[i*O + f] = (float)(dv * rs * (double)g[f] + (double)be[f]);
}

// ---------------- output stores (flag-branched dtype) ----------------
__global__ void k_store(const float* __restrict__ z3, void* __restrict__ outp,
                        const int* __restrict__ flag){
    int i = blockIdx.x*256 + threadIdx.x;
    float v = z3[i];
    if (*flag) ((unsigned short*)outp)[i] = f2bf(v);
    else       ((float*)outp)[i] = v;
}
__global__ void k_edges(const int* __restrict__ topIdx, const float* __restrict__ ewArr,
                        void* __restrict__ outp, const int* __restrict__ flag){
    int e = blockIdx.x*256 + threadIdx.x;
    if (e >= ETOT) return;
    int s, dn; float w;
    if (e < NE){ s = e >> 4; dn = topIdx[e]; w = ewArr[e]; }
    else       { s = e - NE; dn = s;        w = 1.0f; }
    if (*flag){
        unsigned short* o = (unsigned short*)outp;
        o[OUT0 + e]          = f2bf((float)s);
        o[OUT0 + ETOT + e]   = f2bf((float)dn);
        o[OUT0 + 2*ETOT + e] = f2bf(w);
    } else {
        float* o = (float*)outp;
        o[OUT0 + e]          = (float)s;
        o[OUT0 + ETOT + e]   = (float)dn;
        o[OUT0 + 2*ETOT + e] = w;
    }
}

extern "C" void kernel_launch(void* const* d_in, const int* in_sizes, int n_in,
                              void* d_out, int out_size, void* d_ws, size_t ws_size,
                              hipStream_t stream){
    char* ws = (char*)d_ws;
    int*    flag   = (int*)   (ws + 0);
    float*  w1f    = (float*) (ws + 4096);
    float*  b1f    = (float*) (ws + 36864);
    float*  g1f    = (float*) (ws + 37376);
    float*  be1f   = (float*) (ws + 37888);
    float*  w2f    = (float*) (ws + 38400);
    float*  b2f    = (float*) (ws + 71168);
    float*  g2f    = (float*) (ws + 71424);
    float*  be2f   = (float*) (ws + 71680);
    float*  wpf    = (float*) (ws + 71936);
    float*  bpf    = (float*) (ws + 88320);
    float*  xf     = (float*) (ws + 98304);      // 2 MB          -> 2195456
    float*  nrmf   = (float*) (ws + 2195456);    // 32 KB         -> 2228224
    int*    topIdx = (int*)   (ws + 2260992);    // 512 KB        -> 2785280
    float*  ewArr  = (float*) (ws + 2785280);    // 512 KB        -> 3309568
    double* degD   = (double*)(ws + 3309568);    // 64 KB         -> 3375104
    float*  dinv   = (float*) (ws + 3375104);    // 32 KB         -> 3407872
    float*  h1     = (float*) (ws + 3407872);    // 4 MB          -> 7602176
    float*  agg1   = (float*) (ws + 7602176);    // 4 MB          -> 11796480
    float*  z1     = (float*) (ws + 11796480);   // 4 MB          -> 15990784
    float*  h2     = h1;
    float*  agg2   = agg1;
    float*  z2     = z1;
    float*  z3     = h1;

    k_probe<<<1, 256, 0, stream>>>((const unsigned short*)d_in[0], flag);
    k_cvt<<<(N*D+255)/256, 256, 0, stream>>>(d_in[0], xf,  N*D, flag);
    k_cvt<<<(D*H+255)/256, 256, 0, stream>>>(d_in[1], w1f, D*H, flag);
    k_cvt<<<1, 256, 0, stream>>>(d_in[2], b1f,  H, flag);
    k_cvt<<<1, 256, 0, stream>>>(d_in[3], g1f,  H, flag);
    k_cvt<<<1, 256, 0, stream>>>(d_in[4], be1f, H, flag);
    k_cvt<<<(H*O+255)/256, 256, 0, stream>>>(d_in[5], w2f, H*O, flag);
    k_cvt<<<1, 256, 0, stream>>>(d_in[6], b2f,  O, flag);
    k_cvt<<<1, 256, 0, stream>>>(d_in[7], g2f,  O, flag);
    k_cvt<<<1, 256, 0, stream>>>(d_in[8], be2f, O, flag);
    k_cvt<<<(O*D+255)/256, 256, 0, stream>>>(d_in[9], wpf, O*D, flag);
    k_cvt<<<1, 256, 0, stream>>>(d_in[10], bpf, D, flag);

    k_prep<<<N/64, 64, 0, stream>>>(xf, nrmf);
    k_topk<<<N/8, 256, 0, stream>>>(xf, nrmf, topIdx, ewArr);
    k_deg_init<<<N/256, 256, 0, stream>>>(degD);
    k_deg_scatter<<<NE/256, 256, 0, stream>>>(topIdx, ewArr, degD);
    k_dinv<<<N/256, 256, 0, stream>>>(degD, dinv);

    k_gemm1<<<(N*H)/256, 256, 0, stream>>>(xf, w1f, h1);
    k_agg_init<H><<<(N*H)/256, 256, 0, stream>>>(h1, dinv, agg1);
    k_agg_scat<H><<<NE, H, 0, stream>>>(topIdx, ewArr, dinv, h1, agg1);
    k_post128<<<N, H, 0, stream>>>(agg1, b1f, g1f, be1f, z1);

    k_gemm2<<<(N*O)/256, 256, 0, stream>>>(z1, w2f, h2);
    k_agg_init<O><<<(N*O)/256, 256, 0, stream>>>(h2, dinv, agg2);
    k_agg_scat<O><<<NE, O, 0, stream>>>(topIdx, ewArr, dinv, h2, agg2);
    k_post64<<<N, O, 0, stream>>>(agg2, b2f, g2f, be2f, z2);

    k_proj<<<(N*D)/256, 256, 0, stream>>>(z2, wpf, bpf, z3);
    k_store<<<(N*D)/256, 256, 0, stream>>>(z3, d_out, flag);
    k_edges<<<(ETOT+255)/256, 256, 0, stream>>>(topIdx, ewArr, d_out, flag);
}

// Round 7
// 1173.955 us; speedup vs baseline: 23.0460x; 1.7765x over previous
//
#include <hip/hip_runtime.h>
#include <cstdint>
#include <climits>

#define N 8192
#define D 64
#define H 128
#define O 64
#define KNB 16
#define NE (N*KNB)        // 131072
#define ETOT (NE + N)     // 139264
#define OUT0 (N*D)        // 524288

__device__ __forceinline__ float bf2f(unsigned short u){
    union { unsigned int u; float f; } v; v.u = ((unsigned int)u) << 16; return v.f;
}
__device__ __forceinline__ unsigned short f2bf(float f){
    union { float f; unsigned int u; } v; v.f = f;
    unsigned int r = v.u + 0x7FFFu + ((v.u >> 16) & 1u);   // RNE
    return (unsigned short)(r >> 16);
}

// ---------------- dtype probe: 1=bf16 inputs, 0=fp32 inputs ----------------
__global__ void k_probe(const unsigned short* __restrict__ x, int* __restrict__ flag){
    __shared__ int cnt;
    if (threadIdx.x == 0) cnt = 0;
    __syncthreads();
    unsigned short u = x[2*threadIdx.x];
    int e = (u >> 7) & 0xFF;
    int ok = (u == 0) || (e >= 0x60 && e <= 0x85);
    unsigned long long m = __ballot(ok);
    if ((threadIdx.x & 63) == 0) atomicAdd(&cnt, __popcll(m));
    __syncthreads();
    if (threadIdx.x == 0) *flag = (cnt >= 128) ? 1 : 0;
}

// ---------------- generic input convert -> fp32 ----------------
__global__ void k_cvt(const void* __restrict__ src, float* __restrict__ dst,
                      int n, const int* __restrict__ flag){
    int i = blockIdx.x*256 + threadIdx.x;
    if (i >= n) return;
    if (*flag) dst[i] = bf2f(((const unsigned short*)src)[i]);
    else       dst[i] = ((const float*)src)[i];
}

// ---------------- row norms: EXACT numpy fp32 pairwise semantics ----------------
__global__ void k_prep(const float* __restrict__ xf, float* __restrict__ nrmf){
    int i = blockIdx.x*64 + threadIdx.x;
    const float* xr = xf + i*D;
    float r[8];
    #pragma unroll
    for (int q = 0; q < 8; ++q) r[q] = __fmul_rn(xr[q], xr[q]);
    #pragma unroll
    for (int b = 8; b < 64; b += 8)
        #pragma unroll
        for (int q = 0; q < 8; ++q)
            r[q] = __fadd_rn(r[q], __fmul_rn(xr[b+q], xr[b+q]));
    float s = __fadd_rn(__fadd_rn(__fadd_rn(r[0],r[1]), __fadd_rn(r[2],r[3])),
                        __fadd_rn(__fadd_rn(r[4],r[5]), __fadd_rn(r[6],r[7])));
    nrmf[i] = __fsqrt_rn(s);
}

// ---- async global->LDS stage of one 64-row tile (16 KB), 16B DMA per lane ----
__device__ __forceinline__ void stage_tile(const float* __restrict__ xf,
                                           float* dst, int t, int tid){
    int w = tid >> 6, lane = tid & 63;
    const float* g = xf + t*4096 + w*1024 + lane*4;
    float* l = dst + w*1024 + lane*4;
    #pragma unroll
    for (int c = 0; c < 4; ++c){
        __builtin_amdgcn_global_load_lds(
            (const __attribute__((address_space(1))) void*)(g + c*256),
            (__attribute__((address_space(3))) void*)(l + c*256), 16, 0, 0);
    }
}

// ---------------- topk: 16 q/block, LDS-tiled j rows, double-buffered --------
// Thread (q=tid&15, m=tid>>4): query i = blk*16+q, owns local rows 4m+r
// (j = t*64+4m+r, r=0..3, t ascending -> j ascending per thread -> R3 tie
// semantics preserved). ds_read_b128 is 16-way q-broadcast (4 same-bank
// addresses/instr = free). Merge pool [r*256+tid] conflict-free; cv[tid] and
// stage-3 scan cv[c*16+q2] hit 16 distinct banks.
// NOTE: plain __launch_bounds__(256) — a min-waves/EU arg capped VGPR at 64
// and spilled (R5: 49 GB scratch writes, 27 ms).
__global__ __launch_bounds__(256) void k_topk(const float* __restrict__ xf,
                                              const float* __restrict__ nrmf,
                                              int* __restrict__ topIdx,
                                              float* __restrict__ ewArr){
    __shared__ __align__(16) char smem[35840];
    float* xjt0 = (float*)smem;                // [4096] tile buf A (16 KB)
    float* xjt1 = (float*)(smem + 16384);      // [4096] tile buf B (16 KB)
    // overlay, used only after the tile loop (barrier-separated):
    float* mv = (float*)smem;                  // [4096]
    int*   mi = (int*)(smem + 16384);          // [4096]
    float* cv = (float*)(smem + 32768);        // [256]
    int*   ci = (int*)(smem + 33792);          // [256]
    int*   cp = (int*)(smem + 34816);          // [256]

    int tid = threadIdx.x;
    int q = tid & 15, m = tid >> 4;
    int i = blockIdx.x*16 + q;

    const float4* xip = (const float4*)(xf + (size_t)i*D);
    float4 xi4[16];
    #pragma unroll
    for (int c = 0; c < 16; ++c) xi4[c] = xip[c];
    float ni = nrmf[i];

    float lv[16]; int li[16];
    #pragma unroll
    for (int r = 0; r < 16; ++r){ lv[r] = -3.0e38f; li[r] = INT_MAX; }

    stage_tile(xf, xjt0, 0, tid);
    __syncthreads();

    for (int t = 0; t < 128; ++t){
        float* buf = (t & 1) ? xjt1 : xjt0;
        if (t < 127) stage_tile(xf, (t & 1) ? xjt0 : xjt1, t+1, tid);

        const float4* B0 = (const float4*)(buf + (4*m+0)*64);
        const float4* B1 = (const float4*)(buf + (4*m+1)*64);
        const float4* B2 = (const float4*)(buf + (4*m+2)*64);
        const float4* B3 = (const float4*)(buf + (4*m+3)*64);
        int jb = t*64 + 4*m;
        float n0 = nrmf[jb], n1 = nrmf[jb+1], n2 = nrmf[jb+2], n3 = nrmf[jb+3];

        float a0 = 0.f, a1 = 0.f, a2 = 0.f, a3 = 0.f;
        #pragma unroll
        for (int c = 0; c < 16; ++c){
            float4 xa = xi4[c];
            float4 b0 = B0[c], b1 = B1[c], b2 = B2[c], b3 = B3[c];
            a0 = __fmaf_rn(b0.x, xa.x, a0); a0 = __fmaf_rn(b0.y, xa.y, a0);
            a0 = __fmaf_rn(b0.z, xa.z, a0); a0 = __fmaf_rn(b0.w, xa.w, a0);
            a1 = __fmaf_rn(b1.x, xa.x, a1); a1 = __fmaf_rn(b1.y, xa.y, a1);
            a1 = __fmaf_rn(b1.z, xa.z, a1); a1 = __fmaf_rn(b1.w, xa.w, a1);
            a2 = __fmaf_rn(b2.x, xa.x, a2); a2 = __fmaf_rn(b2.y, xa.y, a2);
            a2 = __fmaf_rn(b2.z, xa.z, a2); a2 = __fmaf_rn(b2.w, xa.w, a2);
            a3 = __fmaf_rn(b3.x, xa.x, a3); a3 = __fmaf_rn(b3.y, xa.y, a3);
            a3 = __fmaf_rn(b3.z, xa.z, a3); a3 = __fmaf_rn(b3.w, xa.w, a3);
        }
        float sims[4];
        sims[0] = __fdiv_rn(a0, __fadd_rn(__fmul_rn(ni, n0), 1e-8f));
        sims[1] = __fdiv_rn(a1, __fadd_rn(__fmul_rn(ni, n1), 1e-8f));
        sims[2] = __fdiv_rn(a2, __fadd_rn(__fmul_rn(ni, n2), 1e-8f));
        sims[3] = __fdiv_rn(a3, __fadd_rn(__fmul_rn(ni, n3), 1e-8f));
        #pragma unroll
        for (int r = 0; r < 4; ++r){
            int j = jb + r;
            float sv = sims[r];
            if (j != i && sv > lv[15]){
                lv[15] = sv; li[15] = j;
                #pragma unroll
                for (int u = 15; u > 0; --u){
                    if (lv[u] > lv[u-1]){
                        float tv = lv[u]; lv[u] = lv[u-1]; lv[u-1] = tv;
                        int ti = li[u]; li[u] = li[u-1]; li[u-1] = ti;
                    }
                }
            }
        }
        __syncthreads();
    }

    // ---- merge phase (overlays tile buffers; last barrier above separates) ----
    #pragma unroll
    for (int r = 0; r < 16; ++r){
        mv[r*256 + tid] = lv[r];
        mi[r*256 + tid] = li[r];
    }
    __syncthreads();

    for (int sel = 0; sel < 16; ++sel){
        float bv = -3.0e38f; int bi = INT_MAX; int bp = 0;
        #pragma unroll
        for (int r = 0; r < 16; ++r){
            int p = r*256 + tid;
            float v = mv[p]; int id = mi[p];
            if (v > bv || (v == bv && id < bi)){ bv = v; bi = id; bp = p; }
        }
        cv[tid] = bv; ci[tid] = bi; cp[tid] = bp;   // [m*16+q] == tid
        __syncthreads();
        if (tid < 16){
            int q2 = tid;
            float fv = -3.0e38f; int fi = INT_MAX; int fp = 0;
            #pragma unroll
            for (int c = 0; c < 16; ++c){
                float v = cv[c*16 + q2]; int id = ci[c*16 + q2];
                if (v > fv || (v == fv && id < fi)){ fv = v; fi = id; fp = cp[c*16 + q2]; }
            }
            int i2 = blockIdx.x*16 + q2;
            topIdx[i2*KNB + sel] = fi;
            ewArr [i2*KNB + sel] = (fv > 0.5f) ? fv : 0.0f;
            mv[fp] = -3.0e38f;
        }
        __syncthreads();
    }
}

// ---------------- degree / dinv ----------------
__global__ void k_deg_init(double* __restrict__ degD){
    int j = blockIdx.x*blockDim.x + threadIdx.x;
    if (j < N) degD[j] = 2.0;
}
__global__ void k_deg_scatter(const int* __restrict__ topIdx, const float* __restrict__ ewArr,
                              double* __restrict__ degD){
    int e = blockIdx.x*blockDim.x + threadIdx.x;
    if (e < NE){
        float w = ewArr[e];
        if (w > 0.0f) atomicAdd(&degD[topIdx[e]], (double)w);
    }
}
__global__ void k_dinv(const double* __restrict__ degD, float* __restrict__ dinv){
    int j = blockIdx.x*blockDim.x + threadIdx.x;
    if (j < N) dinv[j] = (float)(1.0 / sqrt(degD[j]));
}

// ---------------- dense matmuls ----------------
__global__ void k_gemm1(const float* __restrict__ xf, const float* __restrict__ W1,
                        float* __restrict__ h1){
    int id = blockIdx.x*256 + threadIdx.x;
    int i = id >> 7; int f = id & (H-1);
    const float* xr = xf + i*D;
    float acc = 0.f;
    #pragma unroll
    for (int k = 0; k < D; ++k) acc += xr[k] * W1[k*H + f];
    h1[id] = acc;
}
__global__ void k_gemm2(const float* __restrict__ z1, const float* __restrict__ W2,
                        float* __restrict__ h2){
    int id = blockIdx.x*256 + threadIdx.x;
    int i = id >> 6; int f = id & (O-1);
    const float* zr = z1 + i*H;
    float acc = 0.f;
    #pragma unroll
    for (int k = 0; k < H; ++k) acc += zr[k] * W2[k*O + f];
    h2[id] = acc;
}
__global__ void k_proj(const float* __restrict__ z2, const float* __restrict__ Wp,
                       const float* __restrict__ bp, float* __restrict__ z3){
    int id = blockIdx.x*256 + threadIdx.x;
    int i = id >> 6; int f = id & (D-1);
    const float* zr = z2 + i*O;
    float acc = bp[f];
    #pragma unroll
    for (int k = 0; k < O; ++k) acc += zr[k] * Wp[k*D + f];
    z3[id] = acc;
}

// ---------------- GCN aggregation ----------------
template<int F>
__global__ void k_agg_init(const float* __restrict__ h, const float* __restrict__ dinv,
                           float* __restrict__ agg){
    int id = blockIdx.x*256 + threadIdx.x;
    int j = id / F;
    float dj = dinv[j];
    agg[id] = 2.f * dj * dj * h[id];
}
template<int F>
__global__ void k_agg_scat(const int* __restrict__ topIdx, const float* __restrict__ ewArr,
                           const float* __restrict__ dinv, const float* __restrict__ h,
                           float* __restrict__ agg){
    int e = blockIdx.x; int f = threadIdx.x;
    float w = ewArr[e];
    if (w == 0.f) return;
    int s = e >> 4;
    int dn = topIdx[e];
    float c = dinv[s] * w * dinv[dn];
    atomicAdd(&agg[dn*F + f], c * h[s*F + f]);
}

// ---------------- bias + relu + layernorm ----------------
__global__ void k_post128(const float* __restrict__ agg, const float* __restrict__ b,
                          const float* __restrict__ g, const float* __restrict__ be,
                          float* __restrict__ z){
    __shared__ double s2[2];
    __shared__ double s3[2];
    int i = blockIdx.x; int f = threadIdx.x;
    float v = agg[i*H + f] + b[f];
    v = v > 0.f ? v : 0.f;
    int wid = f >> 6;
    double d = (double)v;
    for (int off = 32; off > 0; off >>= 1) d += __shfl_xor(d, off);
    if ((f & 63) == 0) s2[wid] = d;
    __syncthreads();
    double mu = (s2[0] + s2[1]) * (1.0/128.0);
    double dv = (double)v - mu;
    double qq = dv * dv;
    for (int off = 32; off > 0; off >>= 1) qq += __shfl_xor(qq, off);
    if ((f & 63) == 0) s3[wid] = qq;
    __syncthreads();
    double var = (s3[0] + s3[1]) * (1.0/128.0);
    double rs = 1.0 / sqrt(var + 1e-5);
    z[i*H + f] = (float)(dv * rs * (double)g[f] + (double)be[f]);
}
__global__ void k_post64(const float* __restrict__ agg, const float* __restrict__ b,
                         const float* __restrict__ g, const float* __restrict__ be,
                         float* __restrict__ z){
    int i = blockIdx.x; int f = threadIdx.x;
    float v = agg[i*O + f] + b[f];
    v = v > 0.f ? v : 0.f;
    double d = (double)v;
    for (int off = 32; off > 0; off >>= 1) d += __shfl_xor(d, off);
    double mu = d * (1.0/64.0);
    double dv = (double)v - mu;
    double qq = dv * dv;
    for (int off = 32; off > 0; off >>= 1) qq += __shfl_xor(qq, off);
    double var = qq * (1.0/64.0);
    double rs = 1.0 / sqrt(var + 1e-5);
    z[i*O + f] = (float)(dv * rs * (double)g[f] + (double)be[f]);
}

// ---------------- output stores (flag-branched dtype) ----------------
__global__ void k_store(const float* __restrict__ z3, void* __restrict__ outp,
                        const int* __restrict__ flag){
    int i = blockIdx.x*256 + threadIdx.x;
    float v = z3[i];
    if (*flag) ((unsigned short*)outp)[i] = f2bf(v);
    else       ((float*)outp)[i] = v;
}
__global__ void k_edges(const int* __restrict__ topIdx, const float* __restrict__ ewArr,
                        void* __restrict__ outp, const int* __restrict__ flag){
    int e = blockIdx.x*256 + threadIdx.x;
    if (e >= ETOT) return;
    int s, dn; float w;
    if (e < NE){ s = e >> 4; dn = topIdx[e]; w = ewArr[e]; }
    else       { s = e - NE; dn = s;        w = 1.0f; }
    if (*flag){
        unsigned short* o = (unsigned short*)outp;
        o[OUT0 + e]          = f2bf((float)s);
        o[OUT0 + ETOT + e]   = f2bf((float)dn);
        o[OUT0 + 2*ETOT + e] = f2bf(w);
    } else {
        float* o = (float*)outp;
        o[OUT0 + e]          = (float)s;
        o[OUT0 + ETOT + e]   = (float)dn;
        o[OUT0 + 2*ETOT + e] = w;
    }
}

extern "C" void kernel_launch(void* const* d_in, const int* in_sizes, int n_in,
                              void* d_out, int out_size, void* d_ws, size_t ws_size,
                              hipStream_t stream){
    char* ws = (char*)d_ws;
    int*    flag   = (int*)   (ws + 0);
    float*  w1f    = (float*) (ws + 4096);
    float*  b1f    = (float*) (ws + 36864);
    float*  g1f    = (float*) (ws + 37376);
    float*  be1f   = (float*) (ws + 37888);
    float*  w2f    = (float*) (ws + 38400);
    float*  b2f    = (float*) (ws + 71168);
    float*  g2f    = (float*) (ws + 71424);
    float*  be2f   = (float*) (ws + 71680);
    float*  wpf    = (float*) (ws + 71936);
    float*  bpf    = (float*) (ws + 88320);
    float*  xf     = (float*) (ws + 98304);      // 2 MB          -> 2195456
    float*  nrmf   = (float*) (ws + 2195456);    // 32 KB         -> 2228224
    int*    topIdx = (int*)   (ws + 2260992);    // 512 KB        -> 2785280
    float*  ewArr  = (float*) (ws + 2785280);    // 512 KB        -> 3309568
    double* degD   = (double*)(ws + 3309568);    // 64 KB         -> 3375104
    float*  dinv   = (float*) (ws + 3375104);    // 32 KB         -> 3407872
    float*  h1     = (float*) (ws + 3407872);    // 4 MB          -> 7602176
    float*  agg1   = (float*) (ws + 7602176);    // 4 MB          -> 11796480
    float*  z1     = (float*) (ws + 11796480);   // 4 MB          -> 15990784
    float*  h2     = h1;
    float*  agg2   = agg1;
    float*  z2     = z1;
    float*  z3     = h1;

    k_probe<<<1, 256, 0, stream>>>((const unsigned short*)d_in[0], flag);
    k_cvt<<<(N*D+255)/256, 256, 0, stream>>>(d_in[0], xf,  N*D, flag);
    k_cvt<<<(D*H+255)/256, 256, 0, stream>>>(d_in[1], w1f, D*H, flag);
    k_cvt<<<1, 256, 0, stream>>>(d_in[2], b1f,  H, flag);
    k_cvt<<<1, 256, 0, stream>>>(d_in[3], g1f,  H, flag);
    k_cvt<<<1, 256, 0, stream>>>(d_in[4], be1f, H, flag);
    k_cvt<<<(H*O+255)/256, 256, 0, stream>>>(d_in[5], w2f, H*O, flag);
    k_cvt<<<1, 256, 0, stream>>>(d_in[6], b2f,  O, flag);
    k_cvt<<<1, 256, 0, stream>>>(d_in[7], g2f,  O, flag);
    k_cvt<<<1, 256, 0, stream>>>(d_in[8], be2f, O, flag);
    k_cvt<<<(O*D+255)/256, 256, 0, stream>>>(d_in[9], wpf, O*D, flag);
    k_cvt<<<1, 256, 0, stream>>>(d_in[10], bpf, D, flag);

    k_prep<<<N/64, 64, 0, stream>>>(xf, nrmf);
    k_topk<<<N/16, 256, 0, stream>>>(xf, nrmf, topIdx, ewArr);
    k_deg_init<<<N/256, 256, 0, stream>>>(degD);
    k_deg_scatter<<<NE/256, 256, 0, stream>>>(topIdx, ewArr, degD);
    k_dinv<<<N/256, 256, 0, stream>>>(degD, dinv);

    k_gemm1<<<(N*H)/256, 256, 0, stream>>>(xf, w1f, h1);
    k_agg_init<H><<<(N*H)/256, 256, 0, stream>>>(h1, dinv, agg1);
    k_agg_scat<H><<<NE, H, 0, stream>>>(topIdx, ewArr, dinv, h1, agg1);
    k_post128<<<N, H, 0, stream>>>(agg1, b1f, g1f, be1f, z1);

    k_gemm2<<<(N*O)/256, 256, 0, stream>>>(z1, w2f, h2);
    k_agg_init<O><<<(N*O)/256, 256, 0, stream>>>(h2, dinv, agg2);
    k_agg_scat<O><<<NE, O, 0, stream>>>(topIdx, ewArr, dinv, h2, agg2);
    k_post64<<<N, O, 0, stream>>>(agg2, b2f, g2f, be2f, z2);

    k_proj<<<(N*D)/256, 256, 0, stream>>>(z2, wpf, bpf, z3);
    k_store<<<(N*D)/256, 256, 0, stream>>>(z3, d_out, flag);
    k_edges<<<(ETOT+255)/256, 256, 0, stream>>>(topIdx, ewArr, d_out, flag);
}

// Round 8
// 1152.377 us; speedup vs baseline: 23.4775x; 1.0187x over previous
//
#include <hip/hip_runtime.h>
#include <cstdint>
#include <climits>

#define N 8192
#define D 64
#define H 128
#define O 64
#define KNB 16
#define NE (N*KNB)        // 131072
#define ETOT (NE + N)     // 139264
#define OUT0 (N*D)        // 524288
#define NSPLIT 8
#define JSPAN (N/NSPLIT)  // 1024

__device__ __forceinline__ float bf2f(unsigned short u){
    union { unsigned int u; float f; } v; v.u = ((unsigned int)u) << 16; return v.f;
}
__device__ __forceinline__ unsigned short f2bf(float f){
    union { float f; unsigned int u; } v; v.f = f;
    unsigned int r = v.u + 0x7FFFu + ((v.u >> 16) & 1u);   // RNE
    return (unsigned short)(r >> 16);
}

// ---------------- dtype probe: 1=bf16 inputs, 0=fp32 inputs ----------------
__global__ void k_probe(const unsigned short* __restrict__ x, int* __restrict__ flag){
    __shared__ int cnt;
    if (threadIdx.x == 0) cnt = 0;
    __syncthreads();
    unsigned short u = x[2*threadIdx.x];
    int e = (u >> 7) & 0xFF;
    int ok = (u == 0) || (e >= 0x60 && e <= 0x85);
    unsigned long long m = __ballot(ok);
    if ((threadIdx.x & 63) == 0) atomicAdd(&cnt, __popcll(m));
    __syncthreads();
    if (threadIdx.x == 0) *flag = (cnt >= 128) ? 1 : 0;
}

// ---------------- generic input convert -> fp32 ----------------
__global__ void k_cvt(const void* __restrict__ src, float* __restrict__ dst,
                      int n, const int* __restrict__ flag){
    int i = blockIdx.x*256 + threadIdx.x;
    if (i >= n) return;
    if (*flag) dst[i] = bf2f(((const unsigned short*)src)[i]);
    else       dst[i] = ((const float*)src)[i];
}

// ---------------- row norms: EXACT numpy fp32 pairwise semantics ----------------
__global__ void k_prep(const float* __restrict__ xf, float* __restrict__ nrmf){
    int i = blockIdx.x*64 + threadIdx.x;
    const float* xr = xf + i*D;
    float r[8];
    #pragma unroll
    for (int q = 0; q < 8; ++q) r[q] = __fmul_rn(xr[q], xr[q]);
    #pragma unroll
    for (int b = 8; b < 64; b += 8)
        #pragma unroll
        for (int q = 0; q < 8; ++q)
            r[q] = __fadd_rn(r[q], __fmul_rn(xr[b+q], xr[b+q]));
    float s = __fadd_rn(__fadd_rn(__fadd_rn(r[0],r[1]), __fadd_rn(r[2],r[3])),
                        __fadd_rn(__fadd_rn(r[4],r[5]), __fadd_rn(r[6],r[7])));
    nrmf[i] = __fsqrt_rn(s);
}

// ---------------- topk partial: 16 q/block, 1/8 of j-range per block --------
// R4's proven loop (direct global loads, 4 lines/instr + 16-way broadcast),
// grid = 512 q-blocks x 8 j-splits = 4096 blocks -> 4 blocks/CU resident.
// Thread (q=tid&15, m=tid>>4): j0 = split*1024 + m + 32t, j1 = j0+16,
// t=0..31 (ascending per thread -> R3 tie semantics within split).
// Raw (value,index) partial top-16 written per (query, split); k_merge
// combines with the full (value desc, index asc) comparator -> identical
// result to a single global scan.
// NOTE: plain __launch_bounds__(256) — a min-waves/EU arg capped VGPR at 64
// and spilled (R5: 49 GB scratch writes, 27 ms).
__global__ __launch_bounds__(256) void k_topk(const float* __restrict__ xf,
                                              const float* __restrict__ nrmf,
                                              float* __restrict__ partVal,
                                              int* __restrict__ partIdx){
    __shared__ float mv[4096];   // pool: [r*256 + tid] (conflict-free)
    __shared__ int   mi[4096];
    __shared__ float cv[256];
    __shared__ int   ci[256];
    __shared__ int   cp[256];

    int tid = threadIdx.x;
    int q = tid & 15, m = tid >> 4;
    int qb = blockIdx.x & 511;
    int split = blockIdx.x >> 9;
    int i = qb*16 + q;
    int base = split*JSPAN;

    const float4* xip = (const float4*)(xf + (size_t)i*D);
    float4 xi4[16];
    #pragma unroll
    for (int c = 0; c < 16; ++c) xi4[c] = xip[c];
    float ni = nrmf[i];

    float lv[16]; int li[16];
    #pragma unroll
    for (int r = 0; r < 16; ++r){ lv[r] = -3.0e38f; li[r] = INT_MAX; }

    for (int t = 0; t < 32; ++t){
        int j0 = base + m + 32*t;
        int j1 = j0 + 16;
        const float4* A0 = (const float4*)(xf + (size_t)j0*D);
        const float4* A1 = (const float4*)(xf + (size_t)j1*D);
        float a0 = 0.0f, a1 = 0.0f;
        #pragma unroll
        for (int c = 0; c < 16; ++c){
            float4 b0 = A0[c], b1 = A1[c], xa = xi4[c];
            a0 = __fmaf_rn(b0.x, xa.x, a0);
            a0 = __fmaf_rn(b0.y, xa.y, a0);
            a0 = __fmaf_rn(b0.z, xa.z, a0);
            a0 = __fmaf_rn(b0.w, xa.w, a0);
            a1 = __fmaf_rn(b1.x, xa.x, a1);
            a1 = __fmaf_rn(b1.y, xa.y, a1);
            a1 = __fmaf_rn(b1.z, xa.z, a1);
            a1 = __fmaf_rn(b1.w, xa.w, a1);
        }
        float s0 = __fdiv_rn(a0, __fadd_rn(__fmul_rn(ni, nrmf[j0]), 1e-8f));
        float s1 = __fdiv_rn(a1, __fadd_rn(__fmul_rn(ni, nrmf[j1]), 1e-8f));
        if (j0 == i) s0 = -3.0e38f;
        if (j1 == i) s1 = -3.0e38f;
        if (s0 > lv[15]){
            lv[15] = s0; li[15] = j0;
            #pragma unroll
            for (int r = 15; r > 0; --r){
                if (lv[r] > lv[r-1]){
                    float tv = lv[r]; lv[r] = lv[r-1]; lv[r-1] = tv;
                    int ti = li[r]; li[r] = li[r-1]; li[r-1] = ti;
                }
            }
        }
        if (s1 > lv[15]){
            lv[15] = s1; li[15] = j1;
            #pragma unroll
            for (int r = 15; r > 0; --r){
                if (lv[r] > lv[r-1]){
                    float tv = lv[r]; lv[r] = lv[r-1]; lv[r-1] = tv;
                    int ti = li[r]; li[r] = li[r-1]; li[r-1] = ti;
                }
            }
        }
    }

    #pragma unroll
    for (int r = 0; r < 16; ++r){
        mv[r*256 + tid] = lv[r];
        mi[r*256 + tid] = li[r];
    }
    __syncthreads();

    for (int sel = 0; sel < 16; ++sel){
        float bv = -3.0e38f; int bi = INT_MAX; int bp = 0;
        #pragma unroll
        for (int r = 0; r < 16; ++r){
            int p = r*256 + tid;
            float v = mv[p]; int id = mi[p];
            if (v > bv || (v == bv && id < bi)){ bv = v; bi = id; bp = p; }
        }
        cv[tid] = bv; ci[tid] = bi; cp[tid] = bp;   // tid == m*16+q
        __syncthreads();
        if (tid < 16){
            int q2 = tid;
            float fv = -3.0e38f; int fi = INT_MAX; int fp = 0;
            #pragma unroll
            for (int c = 0; c < 16; ++c){
                float v = cv[c*16 + q2]; int id = ci[c*16 + q2];
                if (v > fv || (v == fv && id < fi)){ fv = v; fi = id; fp = cp[c*16 + q2]; }
            }
            int i2 = qb*16 + q2;
            partVal[(size_t)i2*128 + split*16 + sel] = fv;   // raw sim
            partIdx[(size_t)i2*128 + split*16 + sel] = fi;
            mv[fp] = -3.0e38f;
        }
        __syncthreads();
    }
}

// ---------------- final merge: 8 partial lists -> exact top-16 --------------
__global__ void k_merge(const float* __restrict__ pv, const int* __restrict__ pi,
                        int* __restrict__ topIdx, float* __restrict__ ewArr){
    int i = blockIdx.x*256 + threadIdx.x;   // 8192 threads, one query each
    float lv[16]; int li[16];
    #pragma unroll
    for (int r = 0; r < 16; ++r){ lv[r] = -3.0e38f; li[r] = INT_MAX; }
    for (int s = 0; s < 128; ++s){
        float v = pv[(size_t)i*128 + s];
        int  id = pi[(size_t)i*128 + s];
        if (v > lv[15] || (v == lv[15] && id < li[15])){
            lv[15] = v; li[15] = id;
            #pragma unroll
            for (int r = 15; r > 0; --r){
                if (lv[r] > lv[r-1] || (lv[r] == lv[r-1] && li[r] < li[r-1])){
                    float tv = lv[r]; lv[r] = lv[r-1]; lv[r-1] = tv;
                    int ti = li[r]; li[r] = li[r-1]; li[r-1] = ti;
                }
            }
        }
    }
    #pragma unroll
    for (int sel = 0; sel < 16; ++sel){
        topIdx[i*KNB + sel] = li[sel];
        ewArr [i*KNB + sel] = (lv[sel] > 0.5f) ? lv[sel] : 0.0f;
    }
}

// ---------------- degree / dinv ----------------
__global__ void k_deg_init(double* __restrict__ degD){
    int j = blockIdx.x*blockDim.x + threadIdx.x;
    if (j < N) degD[j] = 2.0;
}
__global__ void k_deg_scatter(const int* __restrict__ topIdx, const float* __restrict__ ewArr,
                              double* __restrict__ degD){
    int e = blockIdx.x*blockDim.x + threadIdx.x;
    if (e < NE){
        float w = ewArr[e];
        if (w > 0.0f) atomicAdd(&degD[topIdx[e]], (double)w);
    }
}
__global__ void k_dinv(const double* __restrict__ degD, float* __restrict__ dinv){
    int j = blockIdx.x*blockDim.x + threadIdx.x;
    if (j < N) dinv[j] = (float)(1.0 / sqrt(degD[j]));
}

// ---------------- dense matmuls ----------------
__global__ void k_gemm1(const float* __restrict__ xf, const float* __restrict__ W1,
                        float* __restrict__ h1){
    int id = blockIdx.x*256 + threadIdx.x;
    int i = id >> 7; int f = id & (H-1);
    const float* xr = xf + i*D;
    float acc = 0.f;
    #pragma unroll
    for (int k = 0; k < D; ++k) acc += xr[k] * W1[k*H + f];
    h1[id] = acc;
}
__global__ void k_gemm2(const float* __restrict__ z1, const float* __restrict__ W2,
                        float* __restrict__ h2){
    int id = blockIdx.x*256 + threadIdx.x;
    int i = id >> 6; int f = id & (O-1);
    const float* zr = z1 + i*H;
    float acc = 0.f;
    #pragma unroll
    for (int k = 0; k < H; ++k) acc += zr[k] * W2[k*O + f];
    h2[id] = acc;
}
__global__ void k_proj(const float* __restrict__ z2, const float* __restrict__ Wp,
                       const float* __restrict__ bp, float* __restrict__ z3){
    int id = blockIdx.x*256 + threadIdx.x;
    int i = id >> 6; int f = id & (D-1);
    const float* zr = z2 + i*O;
    float acc = bp[f];
    #pragma unroll
    for (int k = 0; k < O; ++k) acc += zr[k] * Wp[k*D + f];
    z3[id] = acc;
}

// ---------------- GCN aggregation ----------------
template<int F>
__global__ void k_agg_init(const float* __restrict__ h, const float* __restrict__ dinv,
                           float* __restrict__ agg){
    int id = blockIdx.x*256 + threadIdx.x;
    int j = id / F;
    float dj = dinv[j];
    agg[id] = 2.f * dj * dj * h[id];
}
template<int F>
__global__ void k_agg_scat(const int* __restrict__ topIdx, const float* __restrict__ ewArr,
                           const float* __restrict__ dinv, const float* __restrict__ h,
                           float* __restrict__ agg){
    int e = blockIdx.x; int f = threadIdx.x;
    float w = ewArr[e];
    if (w == 0.f) return;
    int s = e >> 4;
    int dn = topIdx[e];
    float c = dinv[s] * w * dinv[dn];
    atomicAdd(&agg[dn*F + f], c * h[s*F + f]);
}

// ---------------- bias + relu + layernorm ----------------
__global__ void k_post128(const float* __restrict__ agg, const float* __restrict__ b,
                          const float* __restrict__ g, const float* __restrict__ be,
                          float* __restrict__ z){
    __shared__ double s2[2];
    __shared__ double s3[2];
    int i = blockIdx.x; int f = threadIdx.x;
    float v = agg[i*H + f] + b[f];
    v = v > 0.f ? v : 0.f;
    int wid = f >> 6;
    double d = (double)v;
    for (int off = 32; off > 0; off >>= 1) d += __shfl_xor(d, off);
    if ((f & 63) == 0) s2[wid] = d;
    __syncthreads();
    double mu = (s2[0] + s2[1]) * (1.0/128.0);
    double dv = (double)v - mu;
    double qq = dv * dv;
    for (int off = 32; off > 0; off >>= 1) qq += __shfl_xor(qq, off);
    if ((f & 63) == 0) s3[wid] = qq;
    __syncthreads();
    double var = (s3[0] + s3[1]) * (1.0/128.0);
    double rs = 1.0 / sqrt(var + 1e-5);
    z[i*H + f] = (float)(dv * rs * (double)g[f] + (double)be[f]);
}
__global__ void k_post64(const float* __restrict__ agg, const float* __restrict__ b,
                         const float* __restrict__ g, const float* __restrict__ be,
                         float* __restrict__ z){
    int i = blockIdx.x; int f = threadIdx.x;
    float v = agg[i*O + f] + b[f];
    v = v > 0.f ? v : 0.f;
    double d = (double)v;
    for (int off = 32; off > 0; off >>= 1) d += __shfl_xor(d, off);
    double mu = d * (1.0/64.0);
    double dv = (double)v - mu;
    double qq = dv * dv;
    for (int off = 32; off > 0; off >>= 1) qq += __shfl_xor(qq, off);
    double var = qq * (1.0/64.0);
    double rs = 1.0 / sqrt(var + 1e-5);
    z[i*O + f] = (float)(dv * rs * (double)g[f] + (double)be[f]);
}

// ---------------- output stores (flag-branched dtype) ----------------
__global__ void k_store(const float* __restrict__ z3, void* __restrict__ outp,
                        const int* __restrict__ flag){
    int i = blockIdx.x*256 + threadIdx.x;
    float v = z3[i];
    if (*flag) ((unsigned short*)outp)[i] = f2bf(v);
    else       ((float*)outp)[i] = v;
}
__global__ void k_edges(const int* __restrict__ topIdx, const float* __restrict__ ewArr,
                        void* __restrict__ outp, const int* __restrict__ flag){
    int e = blockIdx.x*256 + threadIdx.x;
    if (e >= ETOT) return;
    int s, dn; float w;
    if (e < NE){ s = e >> 4; dn = topIdx[e]; w = ewArr[e]; }
    else       { s = e - NE; dn = s;        w = 1.0f; }
    if (*flag){
        unsigned short* o = (unsigned short*)outp;
        o[OUT0 + e]          = f2bf((float)s);
        o[OUT0 + ETOT + e]   = f2bf((float)dn);
        o[OUT0 + 2*ETOT + e] = f2bf(w);
    } else {
        float* o = (float*)outp;
        o[OUT0 + e]          = (float)s;
        o[OUT0 + ETOT + e]   = (float)dn;
        o[OUT0 + 2*ETOT + e] = w;
    }
}

extern "C" void kernel_launch(void* const* d_in, const int* in_sizes, int n_in,
                              void* d_out, int out_size, void* d_ws, size_t ws_size,
                              hipStream_t stream){
    char* ws = (char*)d_ws;
    int*    flag   = (int*)   (ws + 0);
    float*  w1f    = (float*) (ws + 4096);
    float*  b1f    = (float*) (ws + 36864);
    float*  g1f    = (float*) (ws + 37376);
    float*  be1f   = (float*) (ws + 37888);
    float*  w2f    = (float*) (ws + 38400);
    float*  b2f    = (float*) (ws + 71168);
    float*  g2f    = (float*) (ws + 71424);
    float*  be2f   = (float*) (ws + 71680);
    float*  wpf    = (float*) (ws + 71936);
    float*  bpf    = (float*) (ws + 88320);
    float*  xf     = (float*) (ws + 98304);      // 2 MB          -> 2195456
    float*  nrmf   = (float*) (ws + 2195456);    // 32 KB         -> 2228224
    int*    topIdx = (int*)   (ws + 2260992);    // 512 KB        -> 2785280
    float*  ewArr  = (float*) (ws + 2785280);    // 512 KB        -> 3309568
    double* degD   = (double*)(ws + 3309568);    // 64 KB         -> 3375104
    float*  dinv   = (float*) (ws + 3375104);    // 32 KB         -> 3407872
    float*  h1     = (float*) (ws + 3407872);    // 4 MB          -> 7602176
    float*  agg1   = (float*) (ws + 7602176);    // 4 MB          -> 11796480
    float*  z1     = (float*) (ws + 11796480);   // 4 MB          -> 15990784
    float*  h2     = h1;
    float*  agg2   = agg1;
    float*  z2     = z1;
    float*  z3     = h1;
    // topk part lists reuse h1/agg1 (dead until gemm1, stream-ordered):
    float*  partVal = h1;                        // 8192*128*4 = 4 MB
    int*    partIdx = (int*)agg1;                // 4 MB

    k_probe<<<1, 256, 0, stream>>>((const unsigned short*)d_in[0], flag);
    k_cvt<<<(N*D+255)/256, 256, 0, stream>>>(d_in[0], xf,  N*D, flag);
    k_cvt<<<(D*H+255)/256, 256, 0, stream>>>(d_in[1], w1f, D*H, flag);
    k_cvt<<<1, 256, 0, stream>>>(d_in[2], b1f,  H, flag);
    k_cvt<<<1, 256, 0, stream>>>(d_in[3], g1f,  H, flag);
    k_cvt<<<1, 256, 0, stream>>>(d_in[4], be1f, H, flag);
    k_cvt<<<(H*O+255)/256, 256, 0, stream>>>(d_in[5], w2f, H*O, flag);
    k_cvt<<<1, 256, 0, stream>>>(d_in[6], b2f,  O, flag);
    k_cvt<<<1, 256, 0, stream>>>(d_in[7], g2f,  O, flag);
    k_cvt<<<1, 256, 0, stream>>>(d_in[8], be2f, O, flag);
    k_cvt<<<(O*D+255)/256, 256, 0, stream>>>(d_in[9], wpf, O*D, flag);
    k_cvt<<<1, 256, 0, stream>>>(d_in[10], bpf, D, flag);

    k_prep<<<N/64, 64, 0, stream>>>(xf, nrmf);
    k_topk<<<512*NSPLIT, 256, 0, stream>>>(xf, nrmf, partVal, partIdx);
    k_merge<<<N/256, 256, 0, stream>>>(partVal, partIdx, topIdx, ewArr);
    k_deg_init<<<N/256, 256, 0, stream>>>(degD);
    k_deg_scatter<<<NE/256, 256, 0, stream>>>(topIdx, ewArr, degD);
    k_dinv<<<N/256, 256, 0, stream>>>(degD, dinv);

    k_gemm1<<<(N*H)/256, 256, 0, stream>>>(xf, w1f, h1);
    k_agg_init<H><<<(N*H)/256, 256, 0, stream>>>(h1, dinv, agg1);
    k_agg_scat<H><<<NE, H, 0, stream>>>(topIdx, ewArr, dinv, h1, agg1);
    k_post128<<<N, H, 0, stream>>>(agg1, b1f, g1f, be1f, z1);

    k_gemm2<<<(N*O)/256, 256, 0, stream>>>(z1, w2f, h2);
    k_agg_init<O><<<(N*O)/256, 256, 0, stream>>>(h2, dinv, agg2);
    k_agg_scat<O><<<NE, O, 0, stream>>>(topIdx, ewArr, dinv, h2, agg2);
    k_post64<<<N, O, 0, stream>>>(agg2, b2f, g2f, be2f, z2);

    k_proj<<<(N*D)/256, 256, 0, stream>>>(z2, wpf, bpf, z3);
    k_store<<<(N*D)/256, 256, 0, stream>>>(z3, d_out, flag);
    k_edges<<<(ETOT+255)/256, 256, 0, stream>>>(topIdx, ewArr, d_out, flag);
}

// Round 9
// 1055.465 us; speedup vs baseline: 25.6332x; 1.0918x over previous
//
#include <hip/hip_runtime.h>
#include <cstdint>
#include <climits>

#define N 8192
#define D 64
#define H 128
#define O 64
#define KNB 16
#define NE (N*KNB)        // 131072
#define ETOT (NE + N)     // 139264
#define OUT0 (N*D)        // 524288
#define NSPLIT 2
#define JSPAN (N/NSPLIT)  // 4096

__device__ __forceinline__ float bf2f(unsigned short u){
    union { unsigned int u; float f; } v; v.u = ((unsigned int)u) << 16; return v.f;
}
__device__ __forceinline__ unsigned short f2bf(float f){
    union { float f; unsigned int u; } v; v.f = f;
    unsigned int r = v.u + 0x7FFFu + ((v.u >> 16) & 1u);   // RNE
    return (unsigned short)(r >> 16);
}

// ---------------- dtype probe: 1=bf16 inputs, 0=fp32 inputs ----------------
__global__ void k_probe(const unsigned short* __restrict__ x, int* __restrict__ flag){
    __shared__ int cnt;
    if (threadIdx.x == 0) cnt = 0;
    __syncthreads();
    unsigned short u = x[2*threadIdx.x];
    int e = (u >> 7) & 0xFF;
    int ok = (u == 0) || (e >= 0x60 && e <= 0x85);
    unsigned long long m = __ballot(ok);
    if ((threadIdx.x & 63) == 0) atomicAdd(&cnt, __popcll(m));
    __syncthreads();
    if (threadIdx.x == 0) *flag = (cnt >= 128) ? 1 : 0;
}

// ---------------- generic input convert -> fp32 ----------------
__global__ void k_cvt(const void* __restrict__ src, float* __restrict__ dst,
                      int n, const int* __restrict__ flag){
    int i = blockIdx.x*256 + threadIdx.x;
    if (i >= n) return;
    if (*flag) dst[i] = bf2f(((const unsigned short*)src)[i]);
    else       dst[i] = ((const float*)src)[i];
}

// ---------------- row norms: EXACT numpy fp32 pairwise semantics ----------------
__global__ void k_prep(const float* __restrict__ xf, float* __restrict__ nrmf){
    int i = blockIdx.x*64 + threadIdx.x;
    const float* xr = xf + i*D;
    float r[8];
    #pragma unroll
    for (int q = 0; q < 8; ++q) r[q] = __fmul_rn(xr[q], xr[q]);
    #pragma unroll
    for (int b = 8; b < 64; b += 8)
        #pragma unroll
        for (int q = 0; q < 8; ++q)
            r[q] = __fadd_rn(r[q], __fmul_rn(xr[b+q], xr[b+q]));
    float s = __fadd_rn(__fadd_rn(__fadd_rn(r[0],r[1]), __fadd_rn(r[2],r[3])),
                        __fadd_rn(__fadd_rn(r[4],r[5]), __fadd_rn(r[6],r[7])));
    nrmf[i] = __fsqrt_rn(s);
}

#define INSERT_CAND(SV, JJ)                                                  \
    if ((SV) > lv[15]){                                                      \
        lv[15] = (SV); li[15] = (JJ);                                        \
        _Pragma("unroll")                                                    \
        for (int r = 15; r > 0; --r){                                        \
            if (lv[r] > lv[r-1]){                                            \
                float tv = lv[r]; lv[r] = lv[r-1]; lv[r-1] = tv;             \
                int ti = li[r]; li[r] = li[r-1]; li[r-1] = ti;               \
            }                                                                \
        }                                                                    \
    }

// ---------------- topk partial: 16 q/block, 4 j-chains, 2-way j-split -------
// Thread (q=tid&15, m=tid>>4): query i = qb*16+q; j = base + m + 64t + 16k,
// k=0..3, t=0..63 (strictly ascending per thread -> R3 tie semantics).
// Wave = 16 q x 4 m -> 4 distinct rows per load instr, 16-way broadcast
// (R4-proven best memory shape). 4 independent FMA chains for issue ILP.
// Pool: mv fp32 + mi ushort, [r*256+tid] conflict-free; LDS 27.6 KB (shrunk
// from 35.8 KB to probe the 2-blocks/CU LDS cap seen in R6/R8).
// NOTE: plain __launch_bounds__(256) — a min-waves/EU arg capped VGPR at 64
// and spilled (R5: 49 GB scratch writes, 27 ms).
__global__ __launch_bounds__(256) void k_topk(const float* __restrict__ xf,
                                              const float* __restrict__ nrmf,
                                              float* __restrict__ partVal,
                                              int* __restrict__ partIdx){
    __shared__ float mv[4096];            // 16 KB
    __shared__ unsigned short mi[4096];   // 8 KB
    __shared__ float cv[256];
    __shared__ int   ci[256];
    __shared__ int   cp[256];

    int tid = threadIdx.x;
    int q = tid & 15, m = tid >> 4;
    int qb = blockIdx.x & 511;
    int split = blockIdx.x >> 9;
    int i = qb*16 + q;
    int base = split*JSPAN;

    const float4* xip = (const float4*)(xf + (size_t)i*D);
    float4 xi4[16];
    #pragma unroll
    for (int c = 0; c < 16; ++c) xi4[c] = xip[c];
    float ni = nrmf[i];

    float lv[16]; int li[16];
    #pragma unroll
    for (int r = 0; r < 16; ++r){ lv[r] = -3.0e38f; li[r] = INT_MAX; }

    for (int t = 0; t < 64; ++t){
        int j0 = base + m + 64*t;
        const float4* A0 = (const float4*)(xf + (size_t)j0*D);
        const float4* A1 = (const float4*)(xf + (size_t)(j0+16)*D);
        const float4* A2 = (const float4*)(xf + (size_t)(j0+32)*D);
        const float4* A3 = (const float4*)(xf + (size_t)(j0+48)*D);
        float a0 = 0.f, a1 = 0.f, a2 = 0.f, a3 = 0.f;
        #pragma unroll
        for (int c = 0; c < 16; ++c){
            float4 xa = xi4[c];
            float4 b0 = A0[c], b1 = A1[c], b2 = A2[c], b3 = A3[c];
            a0 = __fmaf_rn(b0.x, xa.x, a0); a0 = __fmaf_rn(b0.y, xa.y, a0);
            a0 = __fmaf_rn(b0.z, xa.z, a0); a0 = __fmaf_rn(b0.w, xa.w, a0);
            a1 = __fmaf_rn(b1.x, xa.x, a1); a1 = __fmaf_rn(b1.y, xa.y, a1);
            a1 = __fmaf_rn(b1.z, xa.z, a1); a1 = __fmaf_rn(b1.w, xa.w, a1);
            a2 = __fmaf_rn(b2.x, xa.x, a2); a2 = __fmaf_rn(b2.y, xa.y, a2);
            a2 = __fmaf_rn(b2.z, xa.z, a2); a2 = __fmaf_rn(b2.w, xa.w, a2);
            a3 = __fmaf_rn(b3.x, xa.x, a3); a3 = __fmaf_rn(b3.y, xa.y, a3);
            a3 = __fmaf_rn(b3.z, xa.z, a3); a3 = __fmaf_rn(b3.w, xa.w, a3);
        }
        float s0 = __fdiv_rn(a0, __fadd_rn(__fmul_rn(ni, nrmf[j0]),    1e-8f));
        float s1 = __fdiv_rn(a1, __fadd_rn(__fmul_rn(ni, nrmf[j0+16]), 1e-8f));
        float s2 = __fdiv_rn(a2, __fadd_rn(__fmul_rn(ni, nrmf[j0+32]), 1e-8f));
        float s3 = __fdiv_rn(a3, __fadd_rn(__fmul_rn(ni, nrmf[j0+48]), 1e-8f));
        if (j0    == i) s0 = -3.0e38f;
        if (j0+16 == i) s1 = -3.0e38f;
        if (j0+32 == i) s2 = -3.0e38f;
        if (j0+48 == i) s3 = -3.0e38f;
        INSERT_CAND(s0, j0)
        INSERT_CAND(s1, j0+16)
        INSERT_CAND(s2, j0+32)
        INSERT_CAND(s3, j0+48)
    }

    #pragma unroll
    for (int r = 0; r < 16; ++r){
        mv[r*256 + tid] = lv[r];
        mi[r*256 + tid] = (unsigned short)li[r];   // all 16 slots hold real j<8192
    }
    __syncthreads();

    for (int sel = 0; sel < 16; ++sel){
        float bv = -3.0e38f; int bi = INT_MAX; int bp = 0;
        #pragma unroll
        for (int r = 0; r < 16; ++r){
            int p = r*256 + tid;
            float v = mv[p]; int id = (int)mi[p];
            if (v > bv || (v == bv && id < bi)){ bv = v; bi = id; bp = p; }
        }
        cv[tid] = bv; ci[tid] = bi; cp[tid] = bp;
        __syncthreads();
        if (tid < 16){
            int q2 = tid;
            float fv = -3.0e38f; int fi = INT_MAX; int fp = 0;
            #pragma unroll
            for (int c = 0; c < 16; ++c){
                float v = cv[c*16 + q2]; int id = ci[c*16 + q2];
                if (v > fv || (v == fv && id < fi)){ fv = v; fi = id; fp = cp[c*16 + q2]; }
            }
            int i2 = qb*16 + q2;
            partVal[(size_t)(split*16 + sel)*N + i2] = fv;   // [s][i] coalesced
            partIdx[(size_t)(split*16 + sel)*N + i2] = fi;
            mv[fp] = -3.0e38f;
        }
        __syncthreads();
    }
}

// ---------------- final merge: 2x16 partial lists -> exact top-16 -----------
__global__ void k_merge(const float* __restrict__ pv, const int* __restrict__ pi,
                        int* __restrict__ topIdx, float* __restrict__ ewArr){
    int i = blockIdx.x*256 + threadIdx.x;   // one query per thread
    float lv[16]; int li[16];
    #pragma unroll
    for (int r = 0; r < 16; ++r){ lv[r] = -3.0e38f; li[r] = INT_MAX; }
    for (int s = 0; s < 16*NSPLIT; ++s){
        float v = pv[(size_t)s*N + i];      // coalesced: lanes consecutive i
        int  id = pi[(size_t)s*N + i];
        if (v > lv[15] || (v == lv[15] && id < li[15])){
            lv[15] = v; li[15] = id;
            #pragma unroll
            for (int r = 15; r > 0; --r){
                if (lv[r] > lv[r-1] || (lv[r] == lv[r-1] && li[r] < li[r-1])){
                    float tv = lv[r]; lv[r] = lv[r-1]; lv[r-1] = tv;
                    int ti = li[r]; li[r] = li[r-1]; li[r-1] = ti;
                }
            }
        }
    }
    #pragma unroll
    for (int sel = 0; sel < 16; ++sel){
        topIdx[i*KNB + sel] = li[sel];
        ewArr [i*KNB + sel] = (lv[sel] > 0.5f) ? lv[sel] : 0.0f;
    }
}

// ---------------- degree / dinv ----------------
__global__ void k_deg_init(double* __restrict__ degD){
    int j = blockIdx.x*blockDim.x + threadIdx.x;
    if (j < N) degD[j] = 2.0;
}
__global__ void k_deg_scatter(const int* __restrict__ topIdx, const float* __restrict__ ewArr,
                              double* __restrict__ degD){
    int e = blockIdx.x*blockDim.x + threadIdx.x;
    if (e < NE){
        float w = ewArr[e];
        if (w > 0.0f) atomicAdd(&degD[topIdx[e]], (double)w);
    }
}
__global__ void k_dinv(const double* __restrict__ degD, float* __restrict__ dinv){
    int j = blockIdx.x*blockDim.x + threadIdx.x;
    if (j < N) dinv[j] = (float)(1.0 / sqrt(degD[j]));
}

// ---------------- dense matmuls ----------------
__global__ void k_gemm1(const float* __restrict__ xf, const float* __restrict__ W1,
                        float* __restrict__ h1){
    int id = blockIdx.x*256 + threadIdx.x;
    int i = id >> 7; int f = id & (H-1);
    const float* xr = xf + i*D;
    float acc = 0.f;
    #pragma unroll
    for (int k = 0; k < D; ++k) acc += xr[k] * W1[k*H + f];
    h1[id] = acc;
}
__global__ void k_gemm2(const float* __restrict__ z1, const float* __restrict__ W2,
                        float* __restrict__ h2){
    int id = blockIdx.x*256 + threadIdx.x;
    int i = id >> 6; int f = id & (O-1);
    const float* zr = z1 + i*H;
    float acc = 0.f;
    #pragma unroll
    for (int k = 0; k < H; ++k) acc += zr[k] * W2[k*O + f];
    h2[id] = acc;
}
__global__ void k_proj(const float* __restrict__ z2, const float* __restrict__ Wp,
                       const float* __restrict__ bp, float* __restrict__ z3){
    int id = blockIdx.x*256 + threadIdx.x;
    int i = id >> 6; int f = id & (D-1);
    const float* zr = z2 + i*O;
    float acc = bp[f];
    #pragma unroll
    for (int k = 0; k < O; ++k) acc += zr[k] * Wp[k*D + f];
    z3[id] = acc;
}

// ---------------- GCN aggregation ----------------
template<int F>
__global__ void k_agg_init(const float* __restrict__ h, const float* __restrict__ dinv,
                           float* __restrict__ agg){
    int id = blockIdx.x*256 + threadIdx.x;
    int j = id / F;
    float dj = dinv[j];
    agg[id] = 2.f * dj * dj * h[id];
}
template<int F>
__global__ void k_agg_scat(const int* __restrict__ topIdx, const float* __restrict__ ewArr,
                           const float* __restrict__ dinv, const float* __restrict__ h,
                           float* __restrict__ agg){
    int e = blockIdx.x; int f = threadIdx.x;
    float w = ewArr[e];
    if (w == 0.f) return;
    int s = e >> 4;
    int dn = topIdx[e];
    float c = dinv[s] * w * dinv[dn];
    atomicAdd(&agg[dn*F + f], c * h[s*F + f]);
}

// ---------------- bias + relu + layernorm ----------------
__global__ void k_post128(const float* __restrict__ agg, const float* __restrict__ b,
                          const float* __restrict__ g, const float* __restrict__ be,
                          float* __restrict__ z){
    __shared__ double s2[2];
    __shared__ double s3[2];
    int i = blockIdx.x; int f = threadIdx.x;
    float v = agg[i*H + f] + b[f];
    v = v > 0.f ? v : 0.f;
    int wid = f >> 6;
    double d = (double)v;
    for (int off = 32; off > 0; off >>= 1) d += __shfl_xor(d, off);
    if ((f & 63) == 0) s2[wid] = d;
    __syncthreads();
    double mu = (s2[0] + s2[1]) * (1.0/128.0);
    double dv = (double)v - mu;
    double qq = dv * dv;
    for (int off = 32; off > 0; off >>= 1) qq += __shfl_xor(qq, off);
    if ((f & 63) == 0) s3[wid] = qq;
    __syncthreads();
    double var = (s3[0] + s3[1]) * (1.0/128.0);
    double rs = 1.0 / sqrt(var + 1e-5);
    z[i*H + f] = (float)(dv * rs * (double)g[f] + (double)be[f]);
}
__global__ void k_post64(const float* __restrict__ agg, const float* __restrict__ b,
                         const float* __restrict__ g, const float* __restrict__ be,
                         float* __restrict__ z){
    int i = blockIdx.x; int f = threadIdx.x;
    float v = agg[i*O + f] + b[f];
    v = v > 0.f ? v : 0.f;
    double d = (double)v;
    for (int off = 32; off > 0; off >>= 1) d += __shfl_xor(d, off);
    double mu = d * (1.0/64.0);
    double dv = (double)v - mu;
    double qq = dv * dv;
    for (int off = 32; off > 0; off >>= 1) qq += __shfl_xor(qq, off);
    double var = qq * (1.0/64.0);
    double rs = 1.0 / sqrt(var + 1e-5);
    z[i*O + f] = (float)(dv * rs * (double)g[f] + (double)be[f]);
}

// ---------------- output stores (flag-branched dtype) ----------------
__global__ void k_store(const float* __restrict__ z3, void* __restrict__ outp,
                        const int* __restrict__ flag){
    int i = blockIdx.x*256 + threadIdx.x;
    float v = z3[i];
    if (*flag) ((unsigned short*)outp)[i] = f2bf(v);
    else       ((float*)outp)[i] = v;
}
__global__ void k_edges(const int* __restrict__ topIdx, const float* __restrict__ ewArr,
                        void* __restrict__ outp, const int* __restrict__ flag){
    int e = blockIdx.x*256 + threadIdx.x;
    if (e >= ETOT) return;
    int s, dn; float w;
    if (e < NE){ s = e >> 4; dn = topIdx[e]; w = ewArr[e]; }
    else       { s = e - NE; dn = s;        w = 1.0f; }
    if (*flag){
        unsigned short* o = (unsigned short*)outp;
        o[OUT0 + e]          = f2bf((float)s);
        o[OUT0 + ETOT + e]   = f2bf((float)dn);
        o[OUT0 + 2*ETOT + e] = f2bf(w);
    } else {
        float* o = (float*)outp;
        o[OUT0 + e]          = (float)s;
        o[OUT0 + ETOT + e]   = (float)dn;
        o[OUT0 + 2*ETOT + e] = w;
    }
}

extern "C" void kernel_launch(void* const* d_in, const int* in_sizes, int n_in,
                              void* d_out, int out_size, void* d_ws, size_t ws_size,
                              hipStream_t stream){
    char* ws = (char*)d_ws;
    int*    flag   = (int*)   (ws + 0);
    float*  w1f    = (float*) (ws + 4096);
    float*  b1f    = (float*) (ws + 36864);
    float*  g1f    = (float*) (ws + 37376);
    float*  be1f   = (float*) (ws + 37888);
    float*  w2f    = (float*) (ws + 38400);
    float*  b2f    = (float*) (ws + 71168);
    float*  g2f    = (float*) (ws + 71424);
    float*  be2f   = (float*) (ws + 71680);
    float*  wpf    = (float*) (ws + 71936);
    float*  bpf    = (float*) (ws + 88320);
    float*  xf     = (float*) (ws + 98304);      // 2 MB          -> 2195456
    float*  nrmf   = (float*) (ws + 2195456);    // 32 KB         -> 2228224
    int*    topIdx = (int*)   (ws + 2260992);    // 512 KB        -> 2785280
    float*  ewArr  = (float*) (ws + 2785280);    // 512 KB        -> 3309568
    double* degD   = (double*)(ws + 3309568);    // 64 KB         -> 3375104
    float*  dinv   = (float*) (ws + 3375104);    // 32 KB         -> 3407872
    float*  h1     = (float*) (ws + 3407872);    // 4 MB          -> 7602176
    float*  agg1   = (float*) (ws + 7602176);    // 4 MB          -> 11796480
    float*  z1     = (float*) (ws + 11796480);   // 4 MB          -> 15990784
    float*  h2     = h1;
    float*  agg2   = agg1;
    float*  z2     = z1;
    float*  z3     = h1;
    // topk part lists reuse h1/agg1 (dead until gemm1, stream-ordered):
    float*  partVal = h1;                        // 32*8192*4 = 1 MB
    int*    partIdx = (int*)agg1;                // 1 MB

    k_probe<<<1, 256, 0, stream>>>((const unsigned short*)d_in[0], flag);
    k_cvt<<<(N*D+255)/256, 256, 0, stream>>>(d_in[0], xf,  N*D, flag);
    k_cvt<<<(D*H+255)/256, 256, 0, stream>>>(d_in[1], w1f, D*H, flag);
    k_cvt<<<1, 256, 0, stream>>>(d_in[2], b1f,  H, flag);
    k_cvt<<<1, 256, 0, stream>>>(d_in[3], g1f,  H, flag);
    k_cvt<<<1, 256, 0, stream>>>(d_in[4], be1f, H, flag);
    k_cvt<<<(H*O+255)/256, 256, 0, stream>>>(d_in[5], w2f, H*O, flag);
    k_cvt<<<1, 256, 0, stream>>>(d_in[6], b2f,  O, flag);
    k_cvt<<<1, 256, 0, stream>>>(d_in[7], g2f,  O, flag);
    k_cvt<<<1, 256, 0, stream>>>(d_in[8], be2f, O, flag);
    k_cvt<<<(O*D+255)/256, 256, 0, stream>>>(d_in[9], wpf, O*D, flag);
    k_cvt<<<1, 256, 0, stream>>>(d_in[10], bpf, D, flag);

    k_prep<<<N/64, 64, 0, stream>>>(xf, nrmf);
    k_topk<<<512*NSPLIT, 256, 0, stream>>>(xf, nrmf, partVal, partIdx);
    k_merge<<<N/256, 256, 0, stream>>>(partVal, partIdx, topIdx, ewArr);
    k_deg_init<<<N/256, 256, 0, stream>>>(degD);
    k_deg_scatter<<<NE/256, 256, 0, stream>>>(topIdx, ewArr, degD);
    k_dinv<<<N/256, 256, 0, stream>>>(degD, dinv);

    k_gemm1<<<(N*H)/256, 256, 0, stream>>>(xf, w1f, h1);
    k_agg_init<H><<<(N*H)/256, 256, 0, stream>>>(h1, dinv, agg1);
    k_agg_scat<H><<<NE, H, 0, stream>>>(topIdx, ewArr, dinv, h1, agg1);
    k_post128<<<N, H, 0, stream>>>(agg1, b1f, g1f, be1f, z1);

    k_gemm2<<<(N*O)/256, 256, 0, stream>>>(z1, w2f, h2);
    k_agg_init<O><<<(N*O)/256, 256, 0, stream>>>(h2, dinv, agg2);
    k_agg_scat<O><<<NE, O, 0, stream>>>(topIdx, ewArr, dinv, h2, agg2);
    k_post64<<<N, O, 0, stream>>>(agg2, b2f, g2f, be2f, z2);

    k_proj<<<(N*D)/256, 256, 0, stream>>>(z2, wpf, bpf, z3);
    k_store<<<(N*D)/256, 256, 0, stream>>>(z3, d_out, flag);
    k_edges<<<(ETOT+255)/256, 256, 0, stream>>>(topIdx, ewArr, d_out, flag);
}